// Round 1
// baseline (1186.641 us; speedup 1.0000x reference)
//
#include <hip/hip_runtime.h>

#define B_ 2
#define CX 64
#define HH 192
#define WW 192
#define HW (HH*WW)
#define HS 48
#define WS 48
#define HWS (HS*WS)
#define CE 160
#define C4 432
#define DG_ 16
#define COUT_D 128

// ---------------- weight transpose: w[o][ci*9+k] -> wT[ci*9+k][o] ----------------
__global__ void transpose_w_kernel(const float* __restrict__ w, float* __restrict__ wT) {
    int i = blockIdx.x * 256 + threadIdx.x;      // 128*1152 = 147456 = 576*256
    int o = i / 1152, ck = i % 1152;
    wT[ck * 128 + o] = w[i];
}

// ---------------- avgpool4 + concat(x, flow, add_feat) ----------------
__global__ void pool_concat_kernel(const float* __restrict__ x, const float* __restrict__ flow,
                                   const float* __restrict__ addf, float* __restrict__ a0) {
    int i = blockIdx.x * 256 + threadIdx.x;      // B*160*48*48 = 737280 = 2880*256
    int xs = i % WS, ys = (i / WS) % HS, c = (i / HWS) % CE, b = i / (HWS * CE);
    const float* src;
    if (c < 64)      src = x    + (size_t)(b * 64 + c) * HW;
    else if (c < 96) src = flow + (size_t)(b * 32 + (c - 64)) * HW;
    else             src = addf + (size_t)(b * 64 + (c - 96)) * HW;
    const float4* s4 = reinterpret_cast<const float4*>(src + (ys * 4) * WW + xs * 4);
    float sum = 0.f;
#pragma unroll
    for (int r = 0; r < 4; ++r) {
        float4 v = s4[r * (WW / 4)];
        sum += v.x + v.y + v.z + v.w;
    }
    a0[i] = sum * (1.f / 16.f);
}

// ---------------- generic 3x3 conv at 48x48, pad=1 ----------------
template<int CIN, int OCPB, bool LRELU>
__global__ __launch_bounds__(256) void conv3x3_kernel(const float* __restrict__ in,
                                                      const float* __restrict__ w,
                                                      const float* __restrict__ bias,
                                                      float* __restrict__ out, int Cout) {
    __shared__ float patch[8 * 18 * 18];
    const int t = threadIdx.x;
    const int tile = blockIdx.x;                 // 9 tiles of 16x16
    const int ty0 = (tile / 3) * 16, tx0 = (tile % 3) * 16;
    const int ocBase = blockIdx.y * OCPB;
    const int b = blockIdx.z;
    const int txx = t & 15, tyy = t >> 4;
    float acc[OCPB];
#pragma unroll
    for (int i = 0; i < OCPB; ++i) acc[i] = 0.f;
    const float* inb = in + (size_t)b * CIN * HWS;

    for (int icc = 0; icc < CIN / 8; ++icc) {
        for (int i = t; i < 8 * 324; i += 256) {
            int ic8 = i / 324, rem = i % 324;
            int yy = rem / 18, xx = rem % 18;
            int gy = ty0 - 1 + yy, gx = tx0 - 1 + xx;
            float v = 0.f;
            if (gy >= 0 && gy < HS && gx >= 0 && gx < WS)
                v = inb[(icc * 8 + ic8) * HWS + gy * WS + gx];
            patch[i] = v;
        }
        __syncthreads();
#pragma unroll
        for (int ic8 = 0; ic8 < 8; ++ic8) {
            float v[9];
#pragma unroll
            for (int dy = 0; dy < 3; ++dy)
#pragma unroll
                for (int dx = 0; dx < 3; ++dx)
                    v[dy * 3 + dx] = patch[ic8 * 324 + (tyy + dy) * 18 + (txx + dx)];
            int icg = icc * 8 + ic8;
#pragma unroll
            for (int oc = 0; oc < OCPB; ++oc) {
                const float* wp = w + ((size_t)(ocBase + oc) * CIN + icg) * 9;
#pragma unroll
                for (int q = 0; q < 9; ++q) acc[oc] = fmaf(wp[q], v[q], acc[oc]);
            }
        }
        __syncthreads();
    }
#pragma unroll
    for (int oc = 0; oc < OCPB; ++oc) {
        float r = acc[oc] + bias[ocBase + oc];
        if (LRELU) r = (r >= 0.f) ? r : 0.2f * r;
        out[((size_t)(b * Cout + ocBase + oc) * HS + (ty0 + tyy)) * WS + (tx0 + txx)] = r;
    }
}

// ---------------- fused: resize+tanh/sigmoid offsets, deform gather, 128x(72x16) GEMM ----------------
__global__ __launch_bounds__(256) void deform_kernel(
    const float* __restrict__ x, const float* __restrict__ addf,
    const float* __restrict__ flow, const float* __restrict__ a4,
    const float* __restrict__ wT, const float* __restrict__ bias,
    float* __restrict__ out)
{
    __shared__ float offs[18 * 64];
    __shared__ float msk[9 * 64];
    __shared__ float val[72 * 64];
    const int t = threadIdx.x;
    const int tile = blockIdx.x, b = blockIdx.y;
    const int ty0 = (tile / (WW / 8)) * 8, tx0 = (tile % (WW / 8)) * 8;
    const int lp = t & 63;
    const int og = __builtin_amdgcn_readfirstlane(t >> 6);   // wave-uniform o-block
    float acc[32];
#pragma unroll
    for (int i = 0; i < 32; ++i) acc[i] = 0.f;
    const float* a4b = a4 + (size_t)b * C4 * HWS;
    const float* flb = flow + (size_t)b * 32 * HW;

    for (int g = 0; g < DG_; ++g) {
        // ---- phase 1: offsets (18 ch) + mask (9 ch) for this tile & group ----
        for (int i = t; i < 27 * 64; i += 256) {
            int ch = i >> 6, p = i & 63;
            int y = ty0 + (p >> 3), xx = tx0 + (p & 7);
            int a4ch = (ch < 18) ? (g * 18 + ch) : (288 + g * 9 + (ch - 18));
            // bilinear 4x upsample, half-pixel, clamped (== jax.image.resize edge renorm)
            float ys = (y + 0.5f) * 0.25f - 0.5f; ys = fminf(fmaxf(ys, 0.f), 47.f);
            float xs = (xx + 0.5f) * 0.25f - 0.5f; xs = fminf(fmaxf(xs, 0.f), 47.f);
            int y0 = (int)ys, x0 = (int)xs;
            float fy = ys - (float)y0, fx = xs - (float)x0;
            int y1 = min(y0 + 1, 47), x1 = min(x0 + 1, 47);
            const float* ap = a4b + (size_t)a4ch * HWS;
            float s00 = ap[y0 * WS + x0], s01 = ap[y0 * WS + x1];
            float s10 = ap[y1 * WS + x0], s11 = ap[y1 * WS + x1];
            float s = (s00 * (1.f - fx) + s01 * fx) * (1.f - fy)
                    + (s10 * (1.f - fx) + s11 * fx) * fy;
            if (ch < 18) {
                int j = ch & 1;                              // 0 = dy, 1 = dx
                // fr3: dy base = flow[2g+1], dx base = flow[2g]
                float base = flb[(size_t)(2 * g + 1 - j) * HW + y * WW + xx];
                offs[ch * 64 + p] = 5.f * tanhf(s) + base;
            } else {
                msk[(ch - 18) * 64 + p] = 1.f / (1.f + expf(-s));
            }
        }
        __syncthreads();
        // ---- phase 2: gather val[c*9+k][p] ----
        for (int i = t; i < 72 * 64; i += 256) {
            int ck = i >> 6, p = i & 63;
            int c = ck / 9, k = ck % 9;
            int y = ty0 + (p >> 3), xx = tx0 + (p & 7);
            float dy = offs[(2 * k) * 64 + p], dx = offs[(2 * k + 1) * 64 + p];
            float m = msk[k * 64 + p];
            float fpy = (float)(y + (k / 3) - 1) + dy;
            float fpx = (float)(xx + (k % 3) - 1) + dx;
            float y0f = floorf(fpy), x0f = floorf(fpx);
            int y0 = (int)y0f, x0 = (int)x0f;
            int y1 = y0 + 1, x1 = x0 + 1;
            float wy = fpy - y0f, wx = fpx - x0f;
            const float* src = (c < 4) ? (x    + (size_t)(b * CX + g * 4 + c) * HW)
                                       : (addf + (size_t)(b * CX + g * 4 + (c - 4)) * HW);
            bool by0 = (unsigned)y0 < (unsigned)HH, by1 = (unsigned)y1 < (unsigned)HH;
            bool bx0 = (unsigned)x0 < (unsigned)WW, bx1 = (unsigned)x1 < (unsigned)WW;
            int y0c = min(max(y0, 0), HH - 1), y1c = min(max(y1, 0), HH - 1);
            int x0c = min(max(x0, 0), WW - 1), x1c = min(max(x1, 0), WW - 1);
            float v00 = src[y0c * WW + x0c], v01 = src[y0c * WW + x1c];
            float v10 = src[y1c * WW + x0c], v11 = src[y1c * WW + x1c];
            float w00 = (by0 && bx0) ? (1.f - wy) * (1.f - wx) : 0.f;
            float w01 = (by0 && bx1) ? (1.f - wy) * wx : 0.f;
            float w10 = (by1 && bx0) ? wy * (1.f - wx) : 0.f;
            float w11 = (by1 && bx1) ? wy * wx : 0.f;
            val[ck * 64 + p] = (v00 * w00 + v01 * w01 + v10 * w10 + v11 * w11) * m;
        }
        __syncthreads();
        // ---- phase 3: acc[o][p] += wT[g*72+ck][o] * val[ck][p] ----
        const float* wg = wT + (size_t)g * 72 * 128 + og * 32;
#pragma unroll 4
        for (int ck = 0; ck < 72; ++ck) {
            float v = val[ck * 64 + lp];
            const float* wp = wg + ck * 128;
#pragma unroll
            for (int oi = 0; oi < 32; ++oi) acc[oi] = fmaf(wp[oi], v, acc[oi]);
        }
        __syncthreads();
    }
    const int py = ty0 + (lp >> 3), px = tx0 + (lp & 7);
#pragma unroll
    for (int oi = 0; oi < 32; ++oi) {
        int o = og * 32 + oi;
        out[((size_t)(b * COUT_D + o) * HH + py) * WW + px] = acc[oi] + bias[o];
    }
}

extern "C" void kernel_launch(void* const* d_in, const int* in_sizes, int n_in,
                              void* d_out, int out_size, void* d_ws, size_t ws_size,
                              hipStream_t stream) {
    const float* x    = (const float*)d_in[0];
    const float* flow = (const float*)d_in[1];
    const float* addf = (const float*)d_in[2];
    const float* w1   = (const float*)d_in[3];
    const float* b1   = (const float*)d_in[4];
    const float* w2   = (const float*)d_in[5];
    const float* b2   = (const float*)d_in[6];
    const float* w3   = (const float*)d_in[7];
    const float* b3   = (const float*)d_in[8];
    const float* w4   = (const float*)d_in[9];
    const float* b4   = (const float*)d_in[10];
    const float* wgt  = (const float*)d_in[11];
    const float* bias = (const float*)d_in[12];
    float* out = (float*)d_out;
    float* ws = (float*)d_ws;

    float* a0 = ws;                  // 737280
    float* a1 = a0 + 737280;         // 294912
    float* a2 = a1 + 294912;         // 294912
    float* a3 = a2 + 294912;         // 294912
    float* a4 = a3 + 294912;         // 1990656
    float* wT = a4 + 1990656;        // 147456   (total ~15 MB)

    transpose_w_kernel<<<576, 256, 0, stream>>>(wgt, wT);
    pool_concat_kernel<<<2880, 256, 0, stream>>>(x, flow, addf, a0);
    conv3x3_kernel<160, 8, true ><<<dim3(9, 8, 2),  256, 0, stream>>>(a0, w1, b1, a1, 64);
    conv3x3_kernel<64,  8, true ><<<dim3(9, 8, 2),  256, 0, stream>>>(a1, w2, b2, a2, 64);
    conv3x3_kernel<64,  8, true ><<<dim3(9, 8, 2),  256, 0, stream>>>(a2, w3, b3, a3, 64);
    conv3x3_kernel<64,  8, false><<<dim3(9, 54, 2), 256, 0, stream>>>(a3, w4, b4, a4, 432);
    deform_kernel<<<dim3(576, 2), 256, 0, stream>>>(x, addf, flow, a4, wT, bias, out);
}

// Round 2
// 478.212 us; speedup vs baseline: 2.4814x; 2.4814x over previous
//
#include <hip/hip_runtime.h>

#define B_ 2
#define CX 64
#define HH 192
#define WW 192
#define HW (HH*WW)
#define HS 48
#define WS 48
#define HWS (HS*WS)
#define CE 160
#define C4 432
#define DG_ 16
#define COUT_D 128

typedef short bf16x8 __attribute__((ext_vector_type(8)));
typedef float f32x4 __attribute__((ext_vector_type(4)));
typedef unsigned short u16;

__device__ __forceinline__ unsigned f2bf(float f) {
    unsigned u = __float_as_uint(f);
    return (u + 0x7FFFu + ((u >> 16) & 1u)) >> 16;   // RNE
}
__device__ __forceinline__ float bf2f(u16 h) {
    return __uint_as_float(((unsigned)h) << 16);
}
__device__ __forceinline__ float tanh_fast(float v) {
    float e = __expf(2.f * v);                        // inf-safe: rcp(inf)=0 -> 1
    return 1.f - 2.f * __builtin_amdgcn_rcpf(e + 1.f);
}
__device__ __forceinline__ float sigmoid_fast(float s) {
    return __builtin_amdgcn_rcpf(1.f + __expf(-s));
}

// ---------------- weight prep: wgt[o][(g*8+c)*9+k] -> wA[o][g*96 + k*8 + c] bf16, pad 72..95=0 ----
__global__ void prep_wA_kernel(const float* __restrict__ w, u16* __restrict__ wA) {
    int i = blockIdx.x * 256 + threadIdx.x;          // 128*1536 = 196608 = 768*256
    int o = i / 1536, col = i % 1536;
    int g = col / 96, r = col % 96;
    u16 v = 0;
    if (r < 72) {
        int k = r >> 3, c = r & 7;
        v = (u16)f2bf(w[(size_t)o * 1152 + (g * 8 + c) * 9 + k]);
    }
    wA[i] = v;
}

// ---------------- x/add_feat -> NHWC-by-group bf16: xg[b][g][y][x][c0..7] ----------------
__global__ void transpose_x_kernel(const float* __restrict__ x, const float* __restrict__ addf,
                                   u16* __restrict__ xg) {
    int i = blockIdx.x * 256 + threadIdx.x;          // 2*16*36864 = 1179648 = 4608*256
    int p = i % HW;
    int g = (i / HW) % DG_;
    int b = i / (HW * DG_);
    const float* xb = x    + ((size_t)(b * CX + g * 4)) * HW + p;
    const float* ab = addf + ((size_t)(b * CX + g * 4)) * HW + p;
    unsigned r0 = f2bf(xb[0])      | (f2bf(xb[HW])     << 16);
    unsigned r1 = f2bf(xb[2 * HW]) | (f2bf(xb[3 * HW]) << 16);
    unsigned r2 = f2bf(ab[0])      | (f2bf(ab[HW])     << 16);
    unsigned r3 = f2bf(ab[2 * HW]) | (f2bf(ab[3 * HW]) << 16);
    *reinterpret_cast<uint4*>(&xg[(size_t)i * 8]) = make_uint4(r0, r1, r2, r3);
}

// ---------------- avgpool4 + concat(x, flow, add_feat) ----------------
__global__ void pool_concat_kernel(const float* __restrict__ x, const float* __restrict__ flow,
                                   const float* __restrict__ addf, float* __restrict__ a0) {
    int i = blockIdx.x * 256 + threadIdx.x;          // 737280 = 2880*256
    int xs = i % WS, ys = (i / WS) % HS, c = (i / HWS) % CE, b = i / (HWS * CE);
    const float* src;
    if (c < 64)      src = x    + (size_t)(b * 64 + c) * HW;
    else if (c < 96) src = flow + (size_t)(b * 32 + (c - 64)) * HW;
    else             src = addf + (size_t)(b * 64 + (c - 96)) * HW;
    const float4* s4 = reinterpret_cast<const float4*>(src + (ys * 4) * WW + xs * 4);
    float sum = 0.f;
#pragma unroll
    for (int r = 0; r < 4; ++r) {
        float4 v = s4[r * (WW / 4)];
        sum += v.x + v.y + v.z + v.w;
    }
    a0[i] = sum * (1.f / 16.f);
}

// ---------------- direct 3x3 conv, one thread per (pixel, OCPT out-ch), scalar weights ----------------
template<int CIN, int OCPT, bool LRELU>
__global__ __launch_bounds__(256) void conv3x3_v2(const float* __restrict__ in,
                                                  const float* __restrict__ w,
                                                  const float* __restrict__ bias,
                                                  float* __restrict__ out, int Cout) {
    const int t = threadIdx.x;
    const int px = blockIdx.x * 256 + t;             // 2304 px (grid.x = 9)
    const int y = px / 48, x = px % 48;
    const int ocB = blockIdx.y * OCPT;
    const int b = blockIdx.z;
    const float* inb = in + (size_t)b * CIN * HWS;
    float acc[OCPT];
#pragma unroll
    for (int o = 0; o < OCPT; ++o) acc[o] = 0.f;
    for (int ic = 0; ic < CIN; ++ic) {
        const float* base = inb + ic * HWS;
        const float* wp = w + ((size_t)ocB * CIN + ic) * 9;
#pragma unroll
        for (int q = 0; q < 9; ++q) {
            int yy = y + q / 3 - 1, xx = x + q % 3 - 1;
            float v = 0.f;
            if ((unsigned)yy < 48u && (unsigned)xx < 48u) v = base[yy * 48 + xx];
#pragma unroll
            for (int o = 0; o < OCPT; ++o)
                acc[o] = fmaf(wp[(size_t)o * CIN * 9 + q], v, acc[o]);
        }
    }
    size_t ob = ((size_t)(b * Cout + ocB)) * HWS + px;
#pragma unroll
    for (int o = 0; o < OCPT; ++o) {
        float r = acc[o] + bias[ocB + o];
        if (LRELU) r = (r >= 0.f) ? r : 0.2f * r;
        out[ob + (size_t)o * HWS] = r;
    }
}

// ---------------- fused deform: offsets (fast tanh/sigmoid) + NHWC gather + MFMA GEMM ----------------
__global__ __launch_bounds__(256) void deform_mfma(
    const u16* __restrict__ xg, const float* __restrict__ flow,
    const float* __restrict__ a4, const u16* __restrict__ wA,
    const float* __restrict__ bias, float* __restrict__ out)
{
    __shared__ float dyb[9 * 64], dxb[9 * 64], mb[9 * 64];
    __shared__ u16 val[64 * 104];                    // [pixel][ck padded 96->104], 2-way bank (free)
    const int t = threadIdx.x;
    const int tile = blockIdx.x, b = blockIdx.y;
    const int ty0 = (tile / 24) * 8, tx0 = (tile % 24) * 8;
    const int lane = t & 63;
    const int og = __builtin_amdgcn_readfirstlane(t >> 6);
    const int l15 = lane & 15, l4 = lane >> 4;

    f32x4 acc[2][4];
#pragma unroll
    for (int m = 0; m < 2; ++m)
#pragma unroll
        for (int n = 0; n < 4; ++n) acc[m][n] = (f32x4){0.f, 0.f, 0.f, 0.f};

    // zero K-pad region (cols 72..103) once; phase 2 only writes cols 0..71
    {
        int row = t >> 2, part = t & 3;              // 256 = 64 rows * 4 parts
        *reinterpret_cast<uint4*>(&val[row * 104 + 72 + part * 8]) = make_uint4(0, 0, 0, 0);
    }

    const float* a4b = a4 + (size_t)b * C4 * HWS;
    const float* flb = flow + (size_t)b * 32 * HW;
    const u16* xgb0 = xg + (size_t)b * DG_ * HW * 8;

    for (int g = 0; g < DG_; ++g) {
        // ---- phase 1: offsets/mask for this tile & group ----
        for (int i = t; i < 27 * 64; i += 256) {
            int ch = i >> 6, p = i & 63;
            int y = ty0 + (p >> 3), xx = tx0 + (p & 7);
            int a4ch = (ch < 18) ? (g * 18 + ch) : (288 + g * 9 + (ch - 18));
            float ys = fminf(fmaxf((y + 0.5f) * 0.25f - 0.5f, 0.f), 47.f);
            float xs = fminf(fmaxf((xx + 0.5f) * 0.25f - 0.5f, 0.f), 47.f);
            int y0 = (int)ys, x0 = (int)xs;
            float fy = ys - (float)y0, fx = xs - (float)x0;
            int y1 = min(y0 + 1, 47), x1 = min(x0 + 1, 47);
            const float* ap = a4b + (size_t)a4ch * HWS;
            float s00 = ap[y0 * WS + x0], s01 = ap[y0 * WS + x1];
            float s10 = ap[y1 * WS + x0], s11 = ap[y1 * WS + x1];
            float s = (s00 * (1.f - fx) + s01 * fx) * (1.f - fy)
                    + (s10 * (1.f - fx) + s11 * fx) * fy;
            if (ch < 18) {
                int k = ch >> 1, comp = ch & 1;      // 0=dy, 1=dx
                float base = flb[(size_t)(2 * g + 1 - comp) * HW + y * WW + xx];
                float v = 5.f * tanh_fast(s) + base;
                if (comp) dxb[k * 64 + p] = v; else dyb[k * 64 + p] = v;
            } else {
                mb[(ch - 18) * 64 + p] = sigmoid_fast(s);
            }
        }
        __syncthreads();
        // ---- phase 2: bilinear gather of 8 channels per (k,pixel) into val bf16 ----
        const u16* xgb = xgb0 + (size_t)g * HW * 8;
        for (int i = t; i < 576; i += 256) {
            int k = i >> 6, p = i & 63;
            int y = ty0 + (p >> 3), xx = tx0 + (p & 7);
            float m = mb[k * 64 + p];
            float fpy = (float)(y + (k / 3) - 1) + dyb[k * 64 + p];
            float fpx = (float)(xx + (k % 3) - 1) + dxb[k * 64 + p];
            float y0f = floorf(fpy), x0f = floorf(fpx);
            int y0 = (int)y0f, x0 = (int)x0f;
            int y1 = y0 + 1, x1 = x0 + 1;
            float wy = fpy - y0f, wx = fpx - x0f;
            bool by0 = (unsigned)y0 < (unsigned)HH, by1 = (unsigned)y1 < (unsigned)HH;
            bool bx0 = (unsigned)x0 < (unsigned)WW, bx1 = (unsigned)x1 < (unsigned)WW;
            int y0c = min(max(y0, 0), HH - 1), y1c = min(max(y1, 0), HH - 1);
            int x0c = min(max(x0, 0), WW - 1), x1c = min(max(x1, 0), WW - 1);
            float w00 = (by0 && bx0) ? (1.f - wy) * (1.f - wx) * m : 0.f;
            float w01 = (by0 && bx1) ? (1.f - wy) * wx * m : 0.f;
            float w10 = (by1 && bx0) ? wy * (1.f - wx) * m : 0.f;
            float w11 = (by1 && bx1) ? wy * wx * m : 0.f;
            uint4 v00 = *reinterpret_cast<const uint4*>(&xgb[(size_t)(y0c * WW + x0c) * 8]);
            uint4 v01 = *reinterpret_cast<const uint4*>(&xgb[(size_t)(y0c * WW + x1c) * 8]);
            uint4 v10 = *reinterpret_cast<const uint4*>(&xgb[(size_t)(y1c * WW + x0c) * 8]);
            uint4 v11 = *reinterpret_cast<const uint4*>(&xgb[(size_t)(y1c * WW + x1c) * 8]);
            const u16* p00 = reinterpret_cast<const u16*>(&v00);
            const u16* p01 = reinterpret_cast<const u16*>(&v01);
            const u16* p10 = reinterpret_cast<const u16*>(&v10);
            const u16* p11 = reinterpret_cast<const u16*>(&v11);
            unsigned pk[4];
#pragma unroll
            for (int cc = 0; cc < 4; ++cc) {
                float lo = w00 * bf2f(p00[2 * cc])     + w01 * bf2f(p01[2 * cc])
                         + w10 * bf2f(p10[2 * cc])     + w11 * bf2f(p11[2 * cc]);
                float hi = w00 * bf2f(p00[2 * cc + 1]) + w01 * bf2f(p01[2 * cc + 1])
                         + w10 * bf2f(p10[2 * cc + 1]) + w11 * bf2f(p11[2 * cc + 1]);
                pk[cc] = f2bf(lo) | (f2bf(hi) << 16);
            }
            *reinterpret_cast<uint4*>(&val[p * 104 + k * 8]) = make_uint4(pk[0], pk[1], pk[2], pk[3]);
        }
        __syncthreads();
        // ---- phase 3: MFMA  acc[128 x 64] += wA[:, g*96..] * val^T ----
        const u16* wg = wA + (size_t)(og * 32) * 1536 + g * 96;
#pragma unroll
        for (int kb = 0; kb < 3; ++kb) {
            bf16x8 a0 = *reinterpret_cast<const bf16x8*>(&wg[(size_t)l15 * 1536 + kb * 32 + l4 * 8]);
            bf16x8 a1 = *reinterpret_cast<const bf16x8*>(&wg[(size_t)(16 + l15) * 1536 + kb * 32 + l4 * 8]);
#pragma unroll
            for (int nf = 0; nf < 4; ++nf) {
                bf16x8 bfrag = *reinterpret_cast<const bf16x8*>(&val[(nf * 16 + l15) * 104 + kb * 32 + l4 * 8]);
                acc[0][nf] = __builtin_amdgcn_mfma_f32_16x16x32_bf16(a0, bfrag, acc[0][nf], 0, 0, 0);
                acc[1][nf] = __builtin_amdgcn_mfma_f32_16x16x32_bf16(a1, bfrag, acc[1][nf], 0, 0, 0);
            }
        }
        __syncthreads();
    }
    // ---- epilogue: D col=lane&15 (pixel), row=(lane>>4)*4+reg (out-ch within 16) ----
#pragma unroll
    for (int mf = 0; mf < 2; ++mf)
#pragma unroll
        for (int nf = 0; nf < 4; ++nf) {
            int pix = nf * 16 + l15;
            int py = ty0 + (pix >> 3), px = tx0 + (pix & 7);
#pragma unroll
            for (int r = 0; r < 4; ++r) {
                int o = og * 32 + mf * 16 + l4 * 4 + r;
                out[((size_t)(b * COUT_D + o) * HH + py) * WW + px] = acc[mf][nf][r] + bias[o];
            }
        }
}

extern "C" void kernel_launch(void* const* d_in, const int* in_sizes, int n_in,
                              void* d_out, int out_size, void* d_ws, size_t ws_size,
                              hipStream_t stream) {
    const float* x    = (const float*)d_in[0];
    const float* flow = (const float*)d_in[1];
    const float* addf = (const float*)d_in[2];
    const float* w1   = (const float*)d_in[3];
    const float* b1   = (const float*)d_in[4];
    const float* w2   = (const float*)d_in[5];
    const float* b2   = (const float*)d_in[6];
    const float* w3   = (const float*)d_in[7];
    const float* b3   = (const float*)d_in[8];
    const float* w4   = (const float*)d_in[9];
    const float* b4   = (const float*)d_in[10];
    const float* wgt  = (const float*)d_in[11];
    const float* bias = (const float*)d_in[12];
    float* out = (float*)d_out;
    float* ws = (float*)d_ws;

    float* a0 = ws;                          // 737280
    float* a1 = a0 + 737280;                 // 294912
    float* a2 = a1 + 294912;                 // 294912
    float* a3 = a2 + 294912;                 // 294912
    float* a4 = a3 + 294912;                 // 1990656
    u16*   wA = (u16*)(a4 + 1990656);        // 196608 u16
    u16*   xg = (u16*)(a4 + 1990656 + 98304);// 9437184 u16   (total ~34 MB)

    prep_wA_kernel   <<<768,  256, 0, stream>>>(wgt, wA);
    transpose_x_kernel<<<4608, 256, 0, stream>>>(x, addf, xg);
    pool_concat_kernel<<<2880, 256, 0, stream>>>(x, flow, addf, a0);
    conv3x3_v2<160, 2, true ><<<dim3(9, 32,  2), 256, 0, stream>>>(a0, w1, b1, a1, 64);
    conv3x3_v2<64,  2, true ><<<dim3(9, 32,  2), 256, 0, stream>>>(a1, w2, b2, a2, 64);
    conv3x3_v2<64,  2, true ><<<dim3(9, 32,  2), 256, 0, stream>>>(a2, w3, b3, a3, 64);
    conv3x3_v2<64,  4, false><<<dim3(9, 108, 2), 256, 0, stream>>>(a3, w4, b4, a4, 432);
    deform_mfma<<<dim3(576, 2), 256, 0, stream>>>(xg, flow, a4, wA, bias, out);
}

// Round 3
// 323.955 us; speedup vs baseline: 3.6630x; 1.4762x over previous
//
#include <hip/hip_runtime.h>

#define B_ 2
#define CX 64
#define HH 192
#define WW 192
#define HW (HH*WW)
#define HS 48
#define WS 48
#define HWS (HS*WS)
#define CE 160
#define C4 432
#define DG_ 16
#define COUT_D 128

typedef short bf16x8 __attribute__((ext_vector_type(8)));
typedef float f32x4 __attribute__((ext_vector_type(4)));
typedef unsigned short u16;

__device__ __forceinline__ unsigned f2bf(float f) {
    unsigned u = __float_as_uint(f);
    return (u + 0x7FFFu + ((u >> 16) & 1u)) >> 16;   // RNE
}
__device__ __forceinline__ float bf2f(u16 h) {
    return __uint_as_float(((unsigned)h) << 16);
}
__device__ __forceinline__ void split_hl(float v, u16& h, u16& l) {
    h = (u16)f2bf(v);
    l = (u16)f2bf(v - bf2f(h));
}
__device__ __forceinline__ float tanh_fast(float v) {
    float e = __expf(2.f * v);
    return 1.f - 2.f * __builtin_amdgcn_rcpf(e + 1.f);
}
__device__ __forceinline__ float sigmoid_fast(float s) {
    return __builtin_amdgcn_rcpf(1.f + __expf(-s));
}

// ---------------- zero page ----------------
__global__ void zero_ws_kernel(float* zp) { zp[threadIdx.x] = 0.f; }

// ---------------- conv weight prep: w[oc][ic][3][3] -> wq[kind][q][ocp][ic] hi/lo bf16 ----------------
__global__ void prep_wq_kernel(const float* __restrict__ w, u16* __restrict__ wq,
                               int OC, int OCP, int CIN) {
    int i = blockIdx.x * 256 + threadIdx.x;          // 2*9*OCP*CIN
    int ic = i % CIN; int rest = i / CIN;
    int oc = rest % OCP; rest /= OCP;
    int q = rest % 9; int kind = rest / 9;
    float v = (oc < OC) ? w[((size_t)oc * CIN + ic) * 9 + q] : 0.f;
    u16 h, l; split_hl(v, h, l);
    wq[i] = kind ? l : h;
}

// ---------------- deform weight prep: wgt[o][(g*8+c)*9+k] -> wA[o][g*96 + k*8 + c] bf16 ----------------
__global__ void prep_wA_kernel(const float* __restrict__ w, u16* __restrict__ wA) {
    int i = blockIdx.x * 256 + threadIdx.x;          // 128*1536 = 768*256
    int o = i / 1536, col = i % 1536;
    int g = col / 96, r = col % 96;
    u16 v = 0;
    if (r < 72) {
        int k = r >> 3, c = r & 7;
        v = (u16)f2bf(w[(size_t)o * 1152 + (g * 8 + c) * 9 + k]);
    }
    wA[i] = v;
}

// ---------------- x/add_feat -> NHWC-by-group bf16: xg[b][g][y][x][c0..7] ----------------
__global__ void transpose_x_kernel(const float* __restrict__ x, const float* __restrict__ addf,
                                   u16* __restrict__ xg) {
    int i = blockIdx.x * 256 + threadIdx.x;          // 4608*256
    int p = i % HW;
    int g = (i / HW) % DG_;
    int b = i / (HW * DG_);
    const float* xb = x    + ((size_t)(b * CX + g * 4)) * HW + p;
    const float* ab = addf + ((size_t)(b * CX + g * 4)) * HW + p;
    unsigned r0 = f2bf(xb[0])      | (f2bf(xb[HW])     << 16);
    unsigned r1 = f2bf(xb[2 * HW]) | (f2bf(xb[3 * HW]) << 16);
    unsigned r2 = f2bf(ab[0])      | (f2bf(ab[HW])     << 16);
    unsigned r3 = f2bf(ab[2 * HW]) | (f2bf(ab[3 * HW]) << 16);
    *reinterpret_cast<uint4*>(&xg[(size_t)i * 8]) = make_uint4(r0, r1, r2, r3);
}

// ---------------- avgpool4 + concat -> NHWC hi/lo bf16 pool_t[b][y][x][kind][160] ----------------
__global__ void pool_concat_t_kernel(const float* __restrict__ x, const float* __restrict__ flow,
                                     const float* __restrict__ addf, u16* __restrict__ pt) {
    int i = blockIdx.x * 256 + threadIdx.x;          // 737280 = 2880*256
    int xs = i % WS, ys = (i / WS) % HS, c = (i / HWS) % CE, b = i / (HWS * CE);
    const float* src;
    if (c < 64)      src = x    + (size_t)(b * 64 + c) * HW;
    else if (c < 96) src = flow + (size_t)(b * 32 + (c - 64)) * HW;
    else             src = addf + (size_t)(b * 64 + (c - 96)) * HW;
    const float4* s4 = reinterpret_cast<const float4*>(src + (ys * 4) * WW + xs * 4);
    float sum = 0.f;
#pragma unroll
    for (int r = 0; r < 4; ++r) {
        float4 v = s4[r * (WW / 4)];
        sum += v.x + v.y + v.z + v.w;
    }
    float v = sum * (1.f / 16.f);
    u16 h, l; split_hl(v, h, l);
    size_t base = ((size_t)(b * HWS + ys * WS + xs) * 2) * CE + c;
    pt[base] = h; pt[base + CE] = l;
}

// ---------------- MFMA 3x3 conv, hi/lo split (3 MFMA per k-step) ----------------
// in_t NHWC hi/lo; block = 4 waves, wave = 16oc x 16px (4x4 tile)
template<int CIN, int OC, int OCP, bool LRELU, bool TO_F32>
__global__ __launch_bounds__(256) void conv_mfma(const u16* __restrict__ in_t,
                                                 const u16* __restrict__ wq,
                                                 const float* __restrict__ bias,
                                                 u16* __restrict__ out_t,
                                                 float* __restrict__ out_f,
                                                 const float* __restrict__ zp) {
    const int t = threadIdx.x;
    const int wv = __builtin_amdgcn_readfirstlane(t >> 6);
    const int l15 = t & 15, l4 = (t >> 4) & 3;
    const int tile = blockIdx.x;
    const int ty0 = (tile / 12) * 4, tx0 = (tile % 12) * 4;
    const int ocb = blockIdx.y * 64 + wv * 16;
    const int b = blockIdx.z;
    const int py = ty0 + (l15 >> 2), pxx = tx0 + (l15 & 3);
    f32x4 ahh = {0,0,0,0}, ahl = {0,0,0,0}, alh = {0,0,0,0};
    const u16* inb = in_t + (size_t)b * (HWS * 2 * CIN);
    const u16* zp16 = (const u16*)zp;
#pragma unroll
    for (int q = 0; q < 9; ++q) {
        int sy = py + q / 3 - 1, sx = pxx + q % 3 - 1;
        bool valid = ((unsigned)sy < 48u) && ((unsigned)sx < 48u);
        const u16* bh = valid ? inb + ((size_t)(sy * 48 + sx) * 2) * CIN : zp16;
        const u16* bl = valid ? inb + ((size_t)(sy * 48 + sx) * 2 + 1) * CIN : zp16;
        const u16* wh = wq + ((size_t)q * OCP + ocb + l15) * CIN + l4 * 8;
        const u16* wl = wq + ((size_t)(9 + q) * OCP + ocb + l15) * CIN + l4 * 8;
#pragma unroll
        for (int kb = 0; kb < CIN / 32; ++kb) {
            bf16x8 Ah = *reinterpret_cast<const bf16x8*>(wh + kb * 32);
            bf16x8 Al = *reinterpret_cast<const bf16x8*>(wl + kb * 32);
            bf16x8 Bh = *reinterpret_cast<const bf16x8*>(bh + kb * 32 + l4 * 8);
            bf16x8 Bl = *reinterpret_cast<const bf16x8*>(bl + kb * 32 + l4 * 8);
            ahh = __builtin_amdgcn_mfma_f32_16x16x32_bf16(Ah, Bh, ahh, 0, 0, 0);
            ahl = __builtin_amdgcn_mfma_f32_16x16x32_bf16(Ah, Bl, ahl, 0, 0, 0);
            alh = __builtin_amdgcn_mfma_f32_16x16x32_bf16(Al, Bh, alh, 0, 0, 0);
        }
    }
#pragma unroll
    for (int r = 0; r < 4; ++r) {
        int oc = ocb + l4 * 4 + r;
        float v = ahh[r] + ahl[r] + alh[r] + ((oc < OC) ? bias[oc] : 0.f);
        if (LRELU) v = (v >= 0.f) ? v : 0.2f * v;
        if (TO_F32) {
            if (oc < OC) out_f[((size_t)(b * OC + oc)) * HWS + py * 48 + pxx] = v;
        } else {
            u16 h, l; split_hl(v, h, l);
            size_t base = ((size_t)(b * HWS + py * 48 + pxx) * 2) * 64 + oc;
            out_t[base] = h; out_t[base + 64] = l;
        }
    }
}

// ---------------- fused deform: staged a4/flow, merged offset+gather, swizzled val, MFMA ----------------
__global__ __launch_bounds__(256) void deform_mfma(
    const u16* __restrict__ xg, const float* __restrict__ flow,
    const float* __restrict__ a4, const u16* __restrict__ wA,
    const float* __restrict__ bias, float* __restrict__ out)
{
    __shared__ u16 val[2][64 * 128];                 // XOR-swizzled 16B units
    __shared__ float a4t[2][27 * 16];                // 4x4 source region x 27 ch
    __shared__ float flds[2][128];                   // [comp][p]
    const int t = threadIdx.x;
    const int tile = blockIdx.x, b = blockIdx.y;
    const int ty0 = (tile / 24) * 8, tx0 = (tile % 24) * 8;
    const int lane = t & 63;
    const int og = __builtin_amdgcn_readfirstlane(t >> 6);
    const int l15 = lane & 15, l4 = lane >> 4;
    const int ys0 = (ty0 >> 2) - 1, xs0 = (tx0 >> 2) - 1;

    f32x4 acc[2][4];
#pragma unroll
    for (int m = 0; m < 2; ++m)
#pragma unroll
        for (int n = 0; n < 4; ++n) acc[m][n] = (f32x4){0.f, 0.f, 0.f, 0.f};

    // zero K-pad units 9..11 of both val buffers (swizzled)
    for (int i = t; i < 384; i += 256) {
        int bb = (i >= 192) ? 1 : 0; int j = i - bb * 192;
        int row = j / 3, u = 9 + j % 3;
        *reinterpret_cast<uint4*>(&val[bb][row * 128 + ((u ^ (row & 7)) << 3)]) = make_uint4(0, 0, 0, 0);
    }

    const float* a4b = a4 + (size_t)b * C4 * HWS;
    const float* flb = flow + (size_t)b * 32 * HW;
    const u16* xgb0 = xg + (size_t)b * DG_ * HW * 8;

#define STAGE(gg, bb) do {                                                          \
    const int gk = (gg);                                                            \
    for (int i = t; i < 432; i += 256) {                                            \
        int ch = i >> 4, idx = i & 15;                                              \
        int gy = min(max(ys0 + (idx >> 2), 0), 47);                                 \
        int gx = min(max(xs0 + (idx & 3), 0), 47);                                  \
        int a4ch = (ch < 18) ? (gk * 18 + ch) : (288 + gk * 9 + (ch - 18));         \
        a4t[bb][i] = a4b[(size_t)a4ch * HWS + gy * 48 + gx];                        \
    }                                                                               \
    if (t < 128) {                                                                  \
        int comp = t >> 6, p = t & 63;                                              \
        int y = ty0 + (p >> 3), xx = tx0 + (p & 7);                                 \
        flds[bb][t] = flb[(size_t)(2 * gk + 1 - comp) * HW + y * WW + xx];          \
    }                                                                               \
} while (0)

#define PH12(gg, bb) do {                                                           \
    const u16* xgb = xgb0 + (size_t)(gg) * HW * 8;                                  \
    for (int i = t; i < 576; i += 256) {                                            \
        int k = i >> 6, p = i & 63;                                                 \
        int y = ty0 + (p >> 3), xx = tx0 + (p & 7);                                 \
        float ysf = fminf(fmaxf((y + 0.5f) * 0.25f - 0.5f, 0.f), 47.f);             \
        float xsf = fminf(fmaxf((xx + 0.5f) * 0.25f - 0.5f, 0.f), 47.f);            \
        int ry0 = (int)ysf, rx0 = (int)xsf;                                         \
        float fy = ysf - (float)ry0, fx = xsf - (float)rx0;                         \
        int base = (ry0 - ys0) * 4 + (rx0 - xs0);                                   \
        float r00 = (1.f - fy) * (1.f - fx), r01 = (1.f - fy) * fx;                 \
        float r10 = fy * (1.f - fx), r11 = fy * fx;                                 \
        const float* A = &a4t[bb][0];                                               \
        float sdy = A[(2*k)*16+base]*r00 + A[(2*k)*16+base+1]*r01                   \
                  + A[(2*k)*16+base+4]*r10 + A[(2*k)*16+base+5]*r11;                \
        float sdx = A[(2*k+1)*16+base]*r00 + A[(2*k+1)*16+base+1]*r01               \
                  + A[(2*k+1)*16+base+4]*r10 + A[(2*k+1)*16+base+5]*r11;            \
        float sm  = A[(18+k)*16+base]*r00 + A[(18+k)*16+base+1]*r01                 \
                  + A[(18+k)*16+base+4]*r10 + A[(18+k)*16+base+5]*r11;              \
        float dyv = 5.f * tanh_fast(sdy) + flds[bb][p];                             \
        float dxv = 5.f * tanh_fast(sdx) + flds[bb][64 + p];                        \
        float m = sigmoid_fast(sm);                                                 \
        float fpy = (float)(y + (k / 3) - 1) + dyv;                                 \
        float fpx = (float)(xx + (k % 3) - 1) + dxv;                                \
        float y0f = floorf(fpy), x0f = floorf(fpx);                                 \
        int gy0 = (int)y0f, gx0 = (int)x0f;                                         \
        int gy1 = gy0 + 1, gx1 = gx0 + 1;                                           \
        float wy = fpy - y0f, wx = fpx - x0f;                                       \
        bool by0 = (unsigned)gy0 < (unsigned)HH, by1 = (unsigned)gy1 < (unsigned)HH;\
        bool bx0 = (unsigned)gx0 < (unsigned)WW, bx1 = (unsigned)gx1 < (unsigned)WW;\
        int y0c = min(max(gy0, 0), HH - 1), y1c = min(max(gy1, 0), HH - 1);         \
        int x0c = min(max(gx0, 0), WW - 1), x1c = min(max(gx1, 0), WW - 1);         \
        float w00 = (by0 && bx0) ? (1.f - wy) * (1.f - wx) * m : 0.f;               \
        float w01 = (by0 && bx1) ? (1.f - wy) * wx * m : 0.f;                       \
        float w10 = (by1 && bx0) ? wy * (1.f - wx) * m : 0.f;                       \
        float w11 = (by1 && bx1) ? wy * wx * m : 0.f;                               \
        uint4 v00 = *reinterpret_cast<const uint4*>(&xgb[(size_t)(y0c * WW + x0c) * 8]); \
        uint4 v01 = *reinterpret_cast<const uint4*>(&xgb[(size_t)(y0c * WW + x1c) * 8]); \
        uint4 v10 = *reinterpret_cast<const uint4*>(&xgb[(size_t)(y1c * WW + x0c) * 8]); \
        uint4 v11 = *reinterpret_cast<const uint4*>(&xgb[(size_t)(y1c * WW + x1c) * 8]); \
        const u16* p00 = reinterpret_cast<const u16*>(&v00);                        \
        const u16* p01 = reinterpret_cast<const u16*>(&v01);                        \
        const u16* p10 = reinterpret_cast<const u16*>(&v10);                        \
        const u16* p11 = reinterpret_cast<const u16*>(&v11);                        \
        unsigned pk[4];                                                             \
        _Pragma("unroll")                                                           \
        for (int cc = 0; cc < 4; ++cc) {                                            \
            float lo = w00 * bf2f(p00[2*cc])   + w01 * bf2f(p01[2*cc])              \
                     + w10 * bf2f(p10[2*cc])   + w11 * bf2f(p11[2*cc]);             \
            float hi = w00 * bf2f(p00[2*cc+1]) + w01 * bf2f(p01[2*cc+1])            \
                     + w10 * bf2f(p10[2*cc+1]) + w11 * bf2f(p11[2*cc+1]);           \
            pk[cc] = f2bf(lo) | (f2bf(hi) << 16);                                   \
        }                                                                           \
        *reinterpret_cast<uint4*>(&val[bb][p * 128 + ((k ^ (p & 7)) << 3)]) =       \
            make_uint4(pk[0], pk[1], pk[2], pk[3]);                                 \
    }                                                                               \
} while (0)

    STAGE(0, 0);
    __syncthreads();

    for (int g = 0; g < DG_; ++g) {
        const int buf = g & 1;
        if (g < 15) STAGE(g + 1, buf ^ 1);
        PH12(g, buf);
        __syncthreads();
        // ---- MFMA: acc[128 x 64] += wA[:, g*96..] * val^T ----
        const u16* wg = wA + (size_t)(og * 32) * 1536 + g * 96;
#pragma unroll
        for (int kb = 0; kb < 3; ++kb) {
            bf16x8 a0 = *reinterpret_cast<const bf16x8*>(wg + (size_t)l15 * 1536 + kb * 32 + l4 * 8);
            bf16x8 a1 = *reinterpret_cast<const bf16x8*>(wg + (size_t)(16 + l15) * 1536 + kb * 32 + l4 * 8);
#pragma unroll
            for (int nf = 0; nf < 4; ++nf) {
                int row = nf * 16 + l15;
                bf16x8 bfrag = *reinterpret_cast<const bf16x8*>(
                    &val[buf][row * 128 + (((kb * 4 + l4) ^ (row & 7)) << 3)]);
                acc[0][nf] = __builtin_amdgcn_mfma_f32_16x16x32_bf16(a0, bfrag, acc[0][nf], 0, 0, 0);
                acc[1][nf] = __builtin_amdgcn_mfma_f32_16x16x32_bf16(a1, bfrag, acc[1][nf], 0, 0, 0);
            }
        }
    }
    // ---- epilogue: D col=lane&15 (pixel), row=(lane>>4)*4+reg (out-ch) ----
#pragma unroll
    for (int mf = 0; mf < 2; ++mf)
#pragma unroll
        for (int nf = 0; nf < 4; ++nf) {
            int pix = nf * 16 + l15;
            int py = ty0 + (pix >> 3), px = tx0 + (pix & 7);
#pragma unroll
            for (int r = 0; r < 4; ++r) {
                int o = og * 32 + mf * 16 + l4 * 4 + r;
                out[((size_t)(b * COUT_D + o) * HH + py) * WW + px] = acc[mf][nf][r] + bias[o];
            }
        }
}

extern "C" void kernel_launch(void* const* d_in, const int* in_sizes, int n_in,
                              void* d_out, int out_size, void* d_ws, size_t ws_size,
                              hipStream_t stream) {
    const float* x    = (const float*)d_in[0];
    const float* flow = (const float*)d_in[1];
    const float* addf = (const float*)d_in[2];
    const float* w1   = (const float*)d_in[3];
    const float* b1   = (const float*)d_in[4];
    const float* w2   = (const float*)d_in[5];
    const float* b2   = (const float*)d_in[6];
    const float* w3   = (const float*)d_in[7];
    const float* b3   = (const float*)d_in[8];
    const float* w4   = (const float*)d_in[9];
    const float* b4   = (const float*)d_in[10];
    const float* wgt  = (const float*)d_in[11];
    const float* bias = (const float*)d_in[12];
    float* out = (float*)d_out;
    float* ws = (float*)d_ws;

    float* zp    = ws;                               // 256 f32
    u16*  pool_t = (u16*)(ws + 256);                 // 1,474,560 u16 (2.95 MB)
    u16*  c1     = pool_t + 1474560;                 // 589,824 u16
    u16*  c2     = c1 + 589824;                      // 589,824 u16
    u16*  c3     = c1;                               // alias (c1 dead after conv2)
    float* a4    = (float*)(c2 + 589824);            // 1,990,656 f32 (8 MB)
    u16*  wq1    = (u16*)(a4 + 1990656);             // 184,320
    u16*  wq2    = wq1 + 184320;                     // 73,728
    u16*  wq3    = wq2 + 73728;                      // 73,728
    u16*  wA     = wq3 + 73728;                      // 196,608
    u16*  xg     = wA + 196608;                      // 9,437,184
    u16*  wq4    = pool_t;                           // alias (pool_t dead after conv1): 516,096

    zero_ws_kernel   <<<1,    256, 0, stream>>>(zp);
    prep_wq_kernel   <<<720,  256, 0, stream>>>(w1, wq1, 64, 64, 160);
    prep_wq_kernel   <<<288,  256, 0, stream>>>(w2, wq2, 64, 64, 64);
    prep_wq_kernel   <<<288,  256, 0, stream>>>(w3, wq3, 64, 64, 64);
    prep_wA_kernel   <<<768,  256, 0, stream>>>(wgt, wA);
    transpose_x_kernel<<<4608, 256, 0, stream>>>(x, addf, xg);
    pool_concat_t_kernel<<<2880, 256, 0, stream>>>(x, flow, addf, pool_t);

    conv_mfma<160, 64, 64, true, false><<<dim3(144, 1, 2), 256, 0, stream>>>(pool_t, wq1, b1, c1, nullptr, zp);
    prep_wq_kernel   <<<2016, 256, 0, stream>>>(w4, wq4, 432, 448, 64);   // into pool_t region
    conv_mfma<64, 64, 64, true, false><<<dim3(144, 1, 2), 256, 0, stream>>>(c1, wq2, b2, c2, nullptr, zp);
    conv_mfma<64, 64, 64, true, false><<<dim3(144, 1, 2), 256, 0, stream>>>(c2, wq3, b3, c3, nullptr, zp);
    conv_mfma<64, 432, 448, false, true><<<dim3(144, 7, 2), 256, 0, stream>>>(c3, wq4, b4, nullptr, a4, zp);

    deform_mfma<<<dim3(576, 2), 256, 0, stream>>>(xg, flow, a4, wA, bias, out);
}